// Round 1
// baseline (636.995 us; speedup 1.0000x reference)
//
#include <hip/hip_runtime.h>
#include <math.h>

typedef unsigned int u32;
typedef float f32x4 __attribute__((ext_vector_type(4)));

#define N_ROWS 1000000      // N
#define NQ     N_ROWS       // float4 quads per (b) slice and per std array
#define KRANK  499999u      // (N-1)/2
#define BPS_P  128
#define CAPW   65536        // candidate capacity per logit group (expected ~1e3)

#define H1_STRIDE 2048      // logit groups use 256 bins, std groups 2048
#define H3_STRIDE 4096      // logit groups use 4096 bins, std groups 512

// ---- ws layout (bytes) ----
#define OFF_STD    0                        // 4M floats = 16,000,000
#define OFF_H1     16000000                 // 24*2048*4 = 196,608
#define OFF_H2     16196608                 // 24*4096*4 = 393,216
#define OFF_H3     16589824                 // 24*4096*4 = 393,216
#define OFF_CNT    16983040                 // 24*4
#define OFF_SEL1   16983136                 // 24*4
#define OFF_KREM1  16983232                 // 24*4
#define OFF_PSEL   16983328                 // 24*4
#define OFF_KREM2  16983424                 // 24*4
#define OFF_SELVAL 16983520                 // 24*4
#define OFF_BCNT   16983616                 // 24*4
#define OFF_TABLE  16983712                 // 640*4 = 2560 (16B aligned)
#define OFF_CAND   16986272                 // 20*65536*4 = 5,242,880 -> ends 22,229,152
#define ZERO_BYTES (OFF_CNT + 96 - OFF_H1)  // h1+h2+h3+cnt = 983,136

__device__ __forceinline__ u32 fkey(float x) {
  u32 b = __float_as_uint(x);
  return (b & 0x80000000u) ? ~b : (b | 0x80000000u);
}
__device__ __forceinline__ float funkey(u32 u) {
  u32 b = (u & 0x80000000u) ? (u & 0x7fffffffu) : ~u;
  return __uint_as_float(b);
}
__device__ __forceinline__ void nt_store4(float4* p, float4 v) {
  f32x4 w = {v.x, v.y, v.z, v.w};
  __builtin_nontemporal_store(w, (f32x4*)p);
}

// K0: 16-pattern x 10-batch x 4 output table. out only depends on mode pattern.
__global__ void k_table(const float* __restrict__ x, const float* __restrict__ dptr,
                        float* __restrict__ table) {
  int t = threadIdx.x;
  if (t >= 160) return;
  int pat = t / 10, b = t % 10;
  float delta = *dptr;
  float xs[4];
  xs[0] = 0.f; xs[1] = x[b*3]; xs[2] = x[b*3+1]; xs[3] = x[b*3+2];
  float dx[4];
  #pragma unroll
  for (int j = 0; j < 4; ++j) dx[j] = delta * (float)((pat >> j) & 1) + xs[j];
  #pragma unroll
  for (int i = 0; i < 4; ++i) {
    float m = -1e30f;
    #pragma unroll
    for (int j = 0; j < 4; ++j) if (j != i) m = fmaxf(m, dx[j]);
    float ssum = 0.f;
    #pragma unroll
    for (int j = 0; j < 4; ++j) if (j != i) ssum += expf(dx[j] - m);
    table[(pat*10 + b)*4 + i] = dx[i] - (logf(ssum) + m);
  }
}

// K1: std over b (ddof=1) for all (n,i); fused level-1 histograms for ALL 24
// groups: logit groups (b<5, 256 bins = sign+7exp) + std groups (2048 bins).
// LDS = 20*256 + 4*2048 = 13312 u32 = 52 KiB -> 3 blocks/CU.
__global__ __launch_bounds__(256) void k_stdhist(const float* __restrict__ logits,
                                                 float* __restrict__ stdv,
                                                 u32* __restrict__ hist1) {
  __shared__ u32 h[20*256 + 4*2048];
  for (int i = threadIdx.x; i < 13312; i += 256) h[i] = 0;
  __syncthreads();
  const float4* L = (const float4*)logits;
  float4* S = (float4*)stdv;
  for (int q = blockIdx.x * 256 + threadIdx.x; q < NQ; q += gridDim.x * 256) {
    float4 v[10];
    #pragma unroll
    for (int b = 0; b < 10; ++b) v[b] = L[b * NQ + q];
    float4 r;
    #pragma unroll
    for (int j = 0; j < 4; ++j) {
      float sum = 0.f;
      #pragma unroll
      for (int b = 0; b < 10; ++b) sum = __fadd_rn(sum, ((const float*)&v[b])[j]);
      float mean = __fdiv_rn(sum, 10.0f);
      float ssd = 0.f;
      #pragma unroll
      for (int b = 0; b < 10; ++b) {
        float d = __fsub_rn(((const float*)&v[b])[j], mean);
        ssd = __fadd_rn(ssd, __fmul_rn(d, d));
      }
      float sd = sqrtf(__fdiv_rn(ssd, 9.0f));
      ((float*)&r)[j] = sd;
      atomicAdd(&h[5120 + j * 2048 + (fkey(sd) >> 21)], 1u);
      #pragma unroll
      for (int b = 0; b < 5; ++b)
        atomicAdd(&h[(b*4 + j) * 256 + (fkey(((const float*)&v[b])[j]) >> 24)], 1u);
    }
    S[q] = r;
  }
  __syncthreads();
  for (int i = threadIdx.x; i < 13312; i += 256) {
    u32 c = h[i];
    if (c) {
      if (i < 5120) atomicAdd(&hist1[(i >> 8) * H1_STRIDE + (i & 255)], c);
      else { int xx = i - 5120; atomicAdd(&hist1[(20 + (xx >> 11)) * H1_STRIDE + (xx & 2047)], c); }
    }
  }
}

// Scan per-group histogram, find bin containing rank k.
// level1: logit nb=256, std nb=2048; writes sel, krem, bincount (exact bin count).
// level2: nb=4096 both; psel = (sel1<<12)|bin.
// level3: logit nb=4096 (selval=funkey((psel<<12)|bin)); std nb=512 ((psel<<9)|bin).
__global__ void k_scan(const u32* __restrict__ hist, int level,
                       const u32* __restrict__ kin, u32* __restrict__ kout,
                       const u32* __restrict__ psel_in, u32* __restrict__ psel_out,
                       float* __restrict__ selval, u32* __restrict__ bincount) {
  int g = blockIdx.x, t = threadIdx.x;
  int nb, stride;
  if (level == 1)      { nb = (g < 20) ? 256 : 2048;  stride = H1_STRIDE; }
  else if (level == 2) { nb = 4096;                    stride = 4096; }
  else                 { nb = (g < 20) ? 4096 : 512;   stride = H3_STRIDE; }
  const u32* h = hist + g * stride;
  int seg = nb >> 8;
  u32 part = 0;
  for (int s = 0; s < seg; ++s) part += h[t * seg + s];
  __shared__ u32 sd[256];
  sd[t] = part;
  __syncthreads();
  for (int off = 1; off < 256; off <<= 1) {
    u32 x = 0;
    if (t >= off) x = sd[t - off];
    __syncthreads();
    sd[t] += x;
    __syncthreads();
  }
  u32 incl = sd[t];
  u32 excl = incl - part;
  u32 k = (level == 1) ? KRANK : kin[g];
  if (k >= excl && k < incl) {
    u32 cum = excl;
    for (int s = 0; s < seg; ++s) {
      u32 c = h[t * seg + s];
      if (k < cum + c) {
        int bin = t * seg + s;
        if (level == 1)      { psel_out[g] = (u32)bin; kout[g] = k - cum; bincount[g] = c; }
        else if (level == 2) { psel_out[g] = (psel_in[g] << 12) | (u32)bin; kout[g] = k - cum; }
        else {
          u32 u = (g < 20) ? ((psel_in[g] << 12) | (u32)bin)
                           : ((psel_in[g] << 9)  | (u32)bin);
          selval[g] = funkey(u);
        }
        break;
      }
      cum += c;
    }
  }
}

// Single full filter pass: logit groups -> compact candidate keys (+ hist2 for
// fallback); std groups -> level-2 histogram.
__global__ __launch_bounds__(256) void k_compact(const float* __restrict__ logits,
                                                 const float* __restrict__ stdv,
                                                 const u32* __restrict__ sel1,
                                                 u32* __restrict__ hist2,
                                                 u32* __restrict__ cnt,
                                                 u32* __restrict__ cand) {
  int blk = blockIdx.x;
  if (blk < 5 * BPS_P) {
    int b = blk / BPS_P, r = blk % BPS_P, gb = b * 4;
    const float4* src = (const float4*)logits + b * NQ;
    u32 s0 = sel1[gb], s1 = sel1[gb+1], s2 = sel1[gb+2], s3 = sel1[gb+3];
    for (int q = r * 256 + threadIdx.x; q < NQ; q += BPS_P * 256) {
      float4 v = src[q];
      u32 u;
      u = fkey(v.x); if ((u >> 24) == s0) { atomicAdd(&hist2[(gb+0)*4096 + ((u>>12)&0xFFFu)],1u); u32 p=atomicAdd(&cnt[gb+0],1u); if (p<CAPW) cand[(gb+0)*CAPW+p]=u; }
      u = fkey(v.y); if ((u >> 24) == s1) { atomicAdd(&hist2[(gb+1)*4096 + ((u>>12)&0xFFFu)],1u); u32 p=atomicAdd(&cnt[gb+1],1u); if (p<CAPW) cand[(gb+1)*CAPW+p]=u; }
      u = fkey(v.z); if ((u >> 24) == s2) { atomicAdd(&hist2[(gb+2)*4096 + ((u>>12)&0xFFFu)],1u); u32 p=atomicAdd(&cnt[gb+2],1u); if (p<CAPW) cand[(gb+2)*CAPW+p]=u; }
      u = fkey(v.w); if ((u >> 24) == s3) { atomicAdd(&hist2[(gb+3)*4096 + ((u>>12)&0xFFFu)],1u); u32 p=atomicAdd(&cnt[gb+3],1u); if (p<CAPW) cand[(gb+3)*CAPW+p]=u; }
    }
  } else {
    int r = blk - 5 * BPS_P;
    const float4* src = (const float4*)stdv;
    u32 s0 = sel1[20], s1 = sel1[21], s2 = sel1[22], s3 = sel1[23];
    for (int q = r * 256 + threadIdx.x; q < NQ; q += BPS_P * 256) {
      float4 v = src[q];
      u32 u;
      u = fkey(v.x); if ((u >> 21) == s0) atomicAdd(&hist2[20*4096 + ((u>>9)&0xFFFu)], 1u);
      u = fkey(v.y); if ((u >> 21) == s1) atomicAdd(&hist2[21*4096 + ((u>>9)&0xFFFu)], 1u);
      u = fkey(v.z); if ((u >> 21) == s2) atomicAdd(&hist2[22*4096 + ((u>>9)&0xFFFu)], 1u);
      u = fkey(v.w); if ((u >> 21) == s3) atomicAdd(&hist2[23*4096 + ((u>>9)&0xFFFu)], 1u);
    }
  }
}

// Exact select of krem1-th smallest among compacted candidates (low 24 bits,
// 3 x 8-bit LDS radix rounds). Skips (fallback path owns it) on overflow.
__global__ __launch_bounds__(256) void k_medsel(const u32* __restrict__ cand,
                                                const u32* __restrict__ bincount,
                                                const u32* __restrict__ sel1,
                                                const u32* __restrict__ krem1,
                                                float* __restrict__ selval) {
  int g = blockIdx.x, t = threadIdx.x;
  u32 n = bincount[g];
  if (n > CAPW) return;
  __shared__ u32 hist[256];
  __shared__ u32 sd[256];
  __shared__ u32 sh_bin, sh_k;
  const u32* c = cand + g * CAPW;
  u32 k = krem1[g];
  u32 pfx = 0;
  #pragma unroll
  for (int rnd = 0; rnd < 3; ++rnd) {
    int sh = 16 - rnd * 8;
    hist[t] = 0;
    __syncthreads();
    for (u32 i = t; i < n; i += 256) {
      u32 u = c[i] & 0xFFFFFFu;
      if ((u >> (sh + 8)) == pfx) atomicAdd(&hist[(u >> sh) & 255u], 1u);
    }
    __syncthreads();
    u32 part = hist[t];
    sd[t] = part;
    __syncthreads();
    for (int off = 1; off < 256; off <<= 1) {
      u32 x = 0;
      if (t >= off) x = sd[t - off];
      __syncthreads();
      sd[t] += x;
      __syncthreads();
    }
    u32 incl = sd[t], excl = incl - part;
    if (k >= excl && k < incl) { sh_bin = (u32)t; sh_k = k - excl; }
    __syncthreads();
    pfx = (pfx << 8) | sh_bin;
    k = sh_k;
    __syncthreads();
  }
  if (t == 0) selval[g] = funkey((sel1[g] << 24) | pfx);
}

// Level-3 histogram: std groups always (16 MB stdv read); logit groups only on
// candidate-overflow (early-exit otherwise -> skips the 80 MB logits read).
__global__ __launch_bounds__(256) void k_filter3(const float* __restrict__ logits,
                                                 const float* __restrict__ stdv,
                                                 const u32* __restrict__ psel,
                                                 const u32* __restrict__ bincount,
                                                 u32* __restrict__ hist3) {
  int blk = blockIdx.x;
  if (blk < 5 * BPS_P) {
    int b = blk / BPS_P, gb = b * 4;
    if (bincount[gb] <= CAPW && bincount[gb+1] <= CAPW &&
        bincount[gb+2] <= CAPW && bincount[gb+3] <= CAPW) return;  // common case
    int r = blk % BPS_P;
    const float4* src = (const float4*)logits + b * NQ;
    u32 s0 = psel[gb], s1 = psel[gb+1], s2 = psel[gb+2], s3 = psel[gb+3];
    for (int q = r * 256 + threadIdx.x; q < NQ; q += BPS_P * 256) {
      float4 v = src[q];
      u32 u;
      u = fkey(v.x); if ((u >> 12) == s0) atomicAdd(&hist3[(gb+0)*H3_STRIDE + (u & 0xFFFu)], 1u);
      u = fkey(v.y); if ((u >> 12) == s1) atomicAdd(&hist3[(gb+1)*H3_STRIDE + (u & 0xFFFu)], 1u);
      u = fkey(v.z); if ((u >> 12) == s2) atomicAdd(&hist3[(gb+2)*H3_STRIDE + (u & 0xFFFu)], 1u);
      u = fkey(v.w); if ((u >> 12) == s3) atomicAdd(&hist3[(gb+3)*H3_STRIDE + (u & 0xFFFu)], 1u);
    }
  } else {
    int r = blk - 5 * BPS_P;
    const float4* src = (const float4*)stdv;
    u32 s0 = psel[20], s1 = psel[21], s2 = psel[22], s3 = psel[23];
    for (int q = r * 256 + threadIdx.x; q < NQ; q += BPS_P * 256) {
      float4 v = src[q];
      u32 u;
      u = fkey(v.x); if ((u >> 9) == s0) atomicAdd(&hist3[20*H3_STRIDE + (u & 0x1FFu)], 1u);
      u = fkey(v.y); if ((u >> 9) == s1) atomicAdd(&hist3[21*H3_STRIDE + (u & 0x1FFu)], 1u);
      u = fkey(v.z); if ((u >> 9) == s2) atomicAdd(&hist3[22*H3_STRIDE + (u & 0x1FFu)], 1u);
      u = fkey(v.w); if ((u >> 9) == s3) atomicAdd(&hist3[23*H3_STRIDE + (u & 0x1FFu)], 1u);
    }
  }
}

// K8: fused mode + out + c. Single fused threshold max(thrA, thrB) — identical
// booleans to (v>=thrA && v>=thrB) for non-NaN data. NT stores for 320 MB out.
__global__ __launch_bounds__(256) void k_final(const float* __restrict__ logits,
                                               const float* __restrict__ selval,
                                               const float* __restrict__ table,
                                               const float* __restrict__ dptr,
                                               float* __restrict__ out) {
  __shared__ float thr[20];
  __shared__ float4 tab[160];
  int t = threadIdx.x;
  if (t < 20) {
    float m  = selval[t];
    float sm = selval[20 + (t & 3)];
    float a = __fadd_rn(m, __fmul_rn(1.96f, sm));   // med + FACTOR*std_med (two roundings, no FMA)
    float b = __fadd_rn(m, __fmul_rn(0.5f, *dptr)); // med + delta/2
    thr[t] = fmaxf(a, b);
  }
  if (t < 160) tab[t] = ((const float4*)table)[t];
  __syncthreads();
  const float4* L = (const float4*)logits;
  float4* O = (float4*)out;
  float4* C = O + 10 * NQ;
  for (int n = blockIdx.x * 256 + t; n < NQ; n += gridDim.x * 256) {
    int s0 = 0, s1 = 0, s2 = 0, s3 = 0;
    #pragma unroll
    for (int b = 0; b < 5; ++b) {
      float4 v = L[b * NQ + n];
      s0 += v.x >= thr[b*4+0];
      s1 += v.y >= thr[b*4+1];
      s2 += v.z >= thr[b*4+2];
      s3 += v.w >= thr[b*4+3];
    }
    int m0 = s0 >= 3, m1 = s1 >= 3, m2 = s2 >= 3, m3 = s3 >= 3;
    int pat = m0 | (m1 << 1) | (m2 << 2) | (m3 << 3);
    float4 cm = make_float4((float)m0, (float)m1, (float)m2, (float)m3);
    #pragma unroll
    for (int b = 0; b < 10; ++b) {
      nt_store4(&O[b * NQ + n], tab[pat * 10 + b]);
      nt_store4(&C[b * NQ + n], cm);
    }
  }
}

extern "C" void kernel_launch(void* const* d_in, const int* in_sizes, int n_in,
                              void* d_out, int out_size, void* d_ws, size_t ws_size,
                              hipStream_t stream) {
  const float* logits = (const float*)d_in[0];
  const float* x      = (const float*)d_in[1];
  const float* dptr   = (const float*)d_in[2];
  float* out = (float*)d_out;
  char* ws = (char*)d_ws;

  float* stdv   = (float*)(ws + OFF_STD);
  u32*   h1     = (u32*)(ws + OFF_H1);
  u32*   h2     = (u32*)(ws + OFF_H2);
  u32*   h3     = (u32*)(ws + OFF_H3);
  u32*   cnt    = (u32*)(ws + OFF_CNT);
  u32*   sel1   = (u32*)(ws + OFF_SEL1);
  u32*   krem1  = (u32*)(ws + OFF_KREM1);
  u32*   psel   = (u32*)(ws + OFF_PSEL);
  u32*   krem2  = (u32*)(ws + OFF_KREM2);
  float* selval = (float*)(ws + OFF_SELVAL);
  u32*   bcnt   = (u32*)(ws + OFF_BCNT);
  float* table  = (float*)(ws + OFF_TABLE);
  u32*   cand   = (u32*)(ws + OFF_CAND);

  hipMemsetAsync(ws + OFF_H1, 0, ZERO_BYTES, stream);

  k_table<<<dim3(1), dim3(192), 0, stream>>>(x, dptr, table);
  k_stdhist<<<dim3(768), dim3(256), 0, stream>>>(logits, stdv, h1);
  k_scan<<<dim3(24), dim3(256), 0, stream>>>(h1, 1, nullptr, krem1, nullptr, sel1, selval, bcnt);
  k_compact<<<dim3(6 * BPS_P), dim3(256), 0, stream>>>(logits, stdv, sel1, h2, cnt, cand);
  k_scan<<<dim3(24), dim3(256), 0, stream>>>(h2, 2, krem1, krem2, sel1, psel, selval, nullptr);
  k_medsel<<<dim3(20), dim3(256), 0, stream>>>(cand, bcnt, sel1, krem1, selval);
  k_filter3<<<dim3(6 * BPS_P), dim3(256), 0, stream>>>(logits, stdv, psel, bcnt, h3);
  k_scan<<<dim3(24), dim3(256), 0, stream>>>(h3, 3, krem2, nullptr, psel, nullptr, selval, nullptr);
  k_final<<<dim3(2048), dim3(256), 0, stream>>>(logits, selval, table, dptr, out);
}